// Round 3
// baseline (88.330 us; speedup 1.0000x reference)
//
#include <hip/hip_runtime.h>
#include <math.h>

#define L_TOT   589      // int(round(fp32(49*1.2f)/0.1))+1
#define L_PAD   592      // pad to multiple of 4 (zeros) for float4 LDS reads
#define NDELAY  30       // int(3/0.1) == 30 (3/0.1 rounds to exactly 30.0 in f64)
#define NSAMP   50
#define HW_PIX  102400   // 320*320
#define STEPF   0.1f
#define BLK     64

// One kernel, no d_ws. Each block rebuilds the shared AIF + sample indices in
// LDS (cheap O(1)-per-point math with exact fp32 compares), then one thread
// per pixel runs two exponential-convolution recurrences (the FFT conv of a
// 2-exp impulse response collapses to S_n = r*S_{n-1} + aif[n]) and emits the
// 50 fp32 signal samples.
__global__ __launch_bounds__(BLK) void dce_kernel(
    const float* __restrict__ param,
    const float* __restrict__ st_g,
    const float* __restrict__ cp_g,
    float* __restrict__ out,          // fp32! reference output dtype is float32
    float M0_trans, float cos_fa, float sig_base)
{
    __shared__ __align__(16) float s_aif[L_PAD];
    __shared__ float s_st[NSAMP], s_cp[NSAMP];
    __shared__ int   s_idx[NSAMP];

    const int tid = threadIdx.x;
    if (tid < NSAMP) { s_st[tid] = st_g[tid]; s_cp[tid] = cp_g[tid]; }
    __syncthreads();

    // AIF: linear interp of Cp onto the 0.1s grid, delayed NDELAY steps.
    // Direct segment index (k-30)/12 with ±1 exact-fp32 adjustment.
    for (int k = tid; k < L_PAD; k += BLK) {
        float v = 0.0f;
        if (k >= NDELAY && k < L_TOT) {
            float t = (float)(k - NDELAY) * STEPF;   // == t_samp[k-30] bitwise
            int j = (k - NDELAY) / 12;               // st spacing 1.2 = 12 grid steps
            if (j > NSAMP - 2) j = NSAMP - 2;
            if (s_st[j + 1] <= t) ++j;               // boundary ulp cases
            if (j > 0 && s_st[j] > t) --j;
            v = s_cp[j] + (t - s_st[j]) * (s_cp[j + 1] - s_cp[j])
                        / (s_st[j + 1] - s_st[j]);
        }
        s_aif[k] = v;
    }
    // searchsorted(t_samp, sample_time, side='left') via 5-wide exact window;
    // JAX gather clamps OOB (last idx 589 -> 588).
    if (tid < NSAMP) {
        float sv = s_st[tid];
        int lo = 12 * tid - 2; if (lo < 0) lo = 0;
        int cnt = lo;                                 // all n < lo satisfy n*0.1f < sv
        for (int n = lo; n <= 12 * tid + 2; ++n)
            if ((float)n * STEPF < sv) cnt = n + 1;   // monotone predicate
        s_idx[tid] = min(cnt, L_TOT - 1);
    }
    __syncthreads();

    const int pix = blockIdx.x * BLK + tid;
    const float ve = param[0 * HW_PIX + pix];
    const float vp = param[1 * HW_PIX + pix];
    const float fp = param[2 * HW_PIX + pix];
    const float ps = param[3 * HW_PIX + pix];

    // params in [0.05,1] => all quantities finite/positive; _nan0 never fires
    const float Te = ve / ps;
    const float T  = (vp + ve) / fp;
    const float Tc = vp / fp;
    const float sm = T + Te;
    const float disc = sqrtf(sm * sm - 4.0f * Tc * Te);  // >= 0.03 always
    const float den2 = 2.0f * Tc * Te;
    const float thp = (sm + disc) / den2;
    const float thm = (sm - disc) / den2;

    const float rm = expf(-STEPF * thm);
    const float rp = expf(-STEPF * thp);

    // normalizers: geometric sums of rm^j / rp^j over the 589-point grid.
    // thm >= 1/60 -> 1-rm >= 1.66e-3: no catastrophic cancellation.
    const float Se = (1.0f - expf(-(STEPF * (float)L_TOT) * thm)) / (1.0f - rm);
    const float Sp = (1.0f - expf(-(STEPF * (float)L_TOT) * thp)) / (1.0f - rp);

    const float we  = 1.0f - Te * thm;   // > 0 (Te*thm < 1)
    const float wpp = Te * thp - 1.0f;   // > 0 (Te*thp > 1)
    const float inv_De = 1.0f / (Se - Sp);             // Se > Sp strictly
    const float inv_Dp = 1.0f / (we * Se + wpp * Sp);  // > 0 strictly

    // conv recurrences: Sm[n] = sum_{k<=n} aif[k]*rm^(n-k); pad zeros harmless
    float Sm = 0.0f, Spv = 0.0f;
    int s = 0;
    int next = s_idx[0];

    const float4* aif4 = (const float4*)s_aif;
    #pragma unroll 2
    for (int q = 0; q < L_PAD / 4; ++q) {
        const float4 a4 = aif4[q];
        const float av[4] = {a4.x, a4.y, a4.z, a4.w};
        #pragma unroll
        for (int u = 0; u < 4; ++u) {
            const int n = 4 * q + u;
            const float a = av[u];
            Sm  = fmaf(Sm,  rm, a);
            Spv = fmaf(Spv, rp, a);
            if (n == next) {                 // wave-uniform: no divergence
                const float ce   = (Sm - Spv) * inv_De;
                const float cpv  = (we * Sm + wpp * Spv) * inv_Dp;
                const float conc = vp * cpv + ve * ce;
                const float E1CA = expf(-0.00487f * fmaf(4.3f, conc, 1.0f));
                const float catr = M0_trans * (1.0f - E1CA)
                                 / (1.0f - E1CA * cos_fa);
                out[s * HW_PIX + pix] = catr + sig_base;
                ++s;
                next = (s < NSAMP) ? s_idx[s] : -1;
            }
        }
    }
}

extern "C" void kernel_launch(void* const* d_in, const int* in_sizes, int n_in,
                              void* d_out, int out_size, void* d_ws, size_t ws_size,
                              hipStream_t stream) {
    const float* param = (const float*)d_in[0];
    const float* st    = (const float*)d_in[1];
    const float* Cp    = (const float*)d_in[2];
    float* out = (float*)d_out;

    // signal-equation constants (host double, then cast)
    double fa   = 10.0 * M_PI / 180.0;
    double cfa  = cos(fa), sfa = sin(fa);
    double E1   = exp(-0.00487);
    double M0   = 100.0 * (1.0 - cfa * E1) / (sfa * (1.0 - E1));
    double M0t  = M0 * sfa;
    double Mst  = M0t * (1.0 - E1) / (1.0 - E1 * cfa);
    float M0_trans = (float)M0t;
    float cos_fa   = (float)cfa;
    float sig_base = (float)(100.0 - Mst);   // ~0 by construction

    dce_kernel<<<HW_PIX / BLK, BLK, 0, stream>>>(param, st, Cp, out,
                                                 M0_trans, cos_fa, sig_base);
}